// Round 1
// baseline (990.078 us; speedup 1.0000x reference)
//
#include <hip/hip_runtime.h>
#include <hip/hip_bf16.h>

#define CCOLS 1000
#define CVEC  250          // 1000 / 4 float4s per row
#define NEG_INF (-3.402823466e38f)

__global__ void zero_out_kernel(float* out) {
    if (threadIdx.x == 0) out[0] = 0.0f;
}

__global__ __launch_bounds__(256, 2)
void row_loss_kernel(const float* __restrict__ score,
                     const float* __restrict__ label,
                     float* __restrict__ out,
                     int nrows, float inv_b) {
    __shared__ float sh_lv[4];
    __shared__ int   sh_li[4];
    __shared__ float sh_sv[4];
    __shared__ float sh_f[4];
    __shared__ float bc_sy;
    __shared__ int   bc_idx;
    __shared__ float bc_M;

    const int tid  = threadIdx.x;
    const int wave = tid >> 6;
    const int lane = tid & 63;
    const bool act = tid < CVEC;

    float acc = 0.0f;

    for (int row = blockIdx.x; row < nrows; row += gridDim.x) {
        const float4* s4p = reinterpret_cast<const float4*>(score + (size_t)row * CCOLS);
        const float4* l4p = reinterpret_cast<const float4*>(label + (size_t)row * CCOLS);
        float4 s4 = make_float4(0.f, 0.f, 0.f, 0.f);
        float4 l4 = make_float4(0.f, 0.f, 0.f, 0.f);
        if (act) { s4 = s4p[tid]; l4 = l4p[tid]; }

        // ---- (1) block argmax of label row, carrying score at that index ----
        float lv = NEG_INF; int li = 0; float sv = 0.0f;
        if (act) {
            const int base = tid * 4;
            lv = l4.x; li = base;     sv = s4.x;
            if (l4.y > lv) { lv = l4.y; li = base + 1; sv = s4.y; }
            if (l4.z > lv) { lv = l4.z; li = base + 2; sv = s4.z; }
            if (l4.w > lv) { lv = l4.w; li = base + 3; sv = s4.w; }
        }
        #pragma unroll
        for (int off = 32; off > 0; off >>= 1) {
            float olv = __shfl_down(lv, off);
            int   oli = __shfl_down(li, off);
            float osv = __shfl_down(sv, off);
            if (olv > lv || (olv == lv && oli < li)) { lv = olv; li = oli; sv = osv; }
        }
        if (lane == 0) { sh_lv[wave] = lv; sh_li[wave] = li; sh_sv[wave] = sv; }
        __syncthreads();                                   // (A)
        if (tid == 0) {
            #pragma unroll
            for (int w = 1; w < 4; ++w) {
                if (sh_lv[w] > lv || (sh_lv[w] == lv && sh_li[w] < li)) {
                    lv = sh_lv[w]; li = sh_li[w]; sv = sh_sv[w];
                }
            }
            bc_idx = li; bc_sy = sv;
        }
        __syncthreads();                                   // (B)
        const int   idx = bc_idx;
        const float s_y = bc_sy;

        // ---- (2) block max of score excluding true class ----
        float mx = NEG_INF;
        if (act) {
            const int base = tid * 4;
            if (base + 0 != idx) mx = fmaxf(mx, s4.x);
            if (base + 1 != idx) mx = fmaxf(mx, s4.y);
            if (base + 2 != idx) mx = fmaxf(mx, s4.z);
            if (base + 3 != idx) mx = fmaxf(mx, s4.w);
        }
        #pragma unroll
        for (int off = 32; off > 0; off >>= 1) mx = fmaxf(mx, __shfl_down(mx, off));
        if (lane == 0) sh_f[wave] = mx;
        __syncthreads();                                   // (C)
        if (tid == 0) bc_M = fmaxf(fmaxf(sh_f[0], sh_f[1]), fmaxf(sh_f[2], sh_f[3]));
        __syncthreads();                                   // (D)
        const float M = bc_M;

        // ---- (3) block sum of exp(score - M) excluding true class ----
        float sum = 0.0f;
        if (act) {
            const int base = tid * 4;
            if (base + 0 != idx) sum += __expf(s4.x - M);
            if (base + 1 != idx) sum += __expf(s4.y - M);
            if (base + 2 != idx) sum += __expf(s4.z - M);
            if (base + 3 != idx) sum += __expf(s4.w - M);
        }
        #pragma unroll
        for (int off = 32; off > 0; off >>= 1) sum += __shfl_down(sum, off);
        if (lane == 0) sh_f[wave] = sum;
        __syncthreads();                                   // (E)
        if (tid == 0) {
            const float S = sh_f[0] + sh_f[1] + sh_f[2] + sh_f[3];
            // loss = tao * logsumexp(m) with tao=1, alph=1:
            //      = (1 + M - s_y) + log(sum_{j != idx} exp(s_j - M))
            acc += (1.0f + M - s_y) + __logf(S);
        }
        // no trailing barrier needed: next writes to sh_* happen only after
        // barriers (A')/(B') of the next iteration, which tid 0 also crosses.
    }

    if (tid == 0) atomicAdd(out, acc * inv_b);
}

extern "C" void kernel_launch(void* const* d_in, const int* in_sizes, int n_in,
                              void* d_out, int out_size, void* d_ws, size_t ws_size,
                              hipStream_t stream) {
    (void)n_in; (void)d_ws; (void)ws_size; (void)out_size;
    const float* score = (const float*)d_in[0];
    const float* label = (const float*)d_in[1];
    float* out = (float*)d_out;

    const int nrows = in_sizes[0] / CCOLS;   // B = 131072
    const float inv_b = 1.0f / (float)nrows;

    zero_out_kernel<<<1, 64, 0, stream>>>(out);

    const int grid = 8192;                   // 16 rows per block, 8192 atomics total
    row_loss_kernel<<<grid, 256, 0, stream>>>(score, label, out, nrows, inv_b);
}